// Round 6
// baseline (207.361 us; speedup 1.0000x reference)
//
#include <hip/hip_runtime.h>
#include <math.h>

typedef unsigned short u16;
typedef __attribute__((ext_vector_type(8))) short short8;    // 8 bf16 = 4 VGPR
typedef __attribute__((ext_vector_type(4))) short short4v;   // 4 bf16 = 2 VGPR
typedef __attribute__((ext_vector_type(4))) float floatx4;   // 16x16 MFMA C/D
typedef __attribute__((ext_vector_type(16))) float floatx16; // 32x32 MFMA C/D

#define DIM 1024
#define SEQ 2048
#define BATCH 4
#define NTOK 8192

// workspace layout (bytes)
#define OFF_XBF   0u
#define OFF_VT    16777216u
#define OFF_WB    33554432u   // 1152 x 1024 bf16 (rows 1056+ never written: poison, discarded)
#define OFF_KANQ  35913728u   // 8192 x 16 bf16
#define OFF_KANK  36438016u
#define OFF_BKAN  36962304u   // 32 floats

__device__ __forceinline__ u16 f2bf(float x) {
  union { float f; unsigned u; } v; v.f = x;
  unsigned r = v.u + 0x7fffu + ((v.u >> 16) & 1u);   // RNE
  return (u16)(r >> 16);
}
__device__ __forceinline__ unsigned fbits(float x) {
  union { float f; unsigned u; } v; v.f = x; return v.u;
}

// ---------------------------------------------------------------------------
// k_misc: one launch for all prep (512 threads/block).
//   bx in [0,32):      wb rows 1024..1055 = bf16(basis @ {Wq,Wk})
//   bx == 32:          bkan[32] = basis @ {bq,bk}
//   bx in [33,2081):   cast x -> xbf (4096 elems/block)
//   bx in [2081,2337): cast Wv -> wb rows 0..1023
// ---------------------------------------------------------------------------
__global__ __launch_bounds__(512) void k_misc(
    const float* __restrict__ x, const float* __restrict__ basis,
    const float* __restrict__ Wq, const float* __restrict__ bq,
    const float* __restrict__ Wk, const float* __restrict__ bk,
    const float* __restrict__ Wv, u16* __restrict__ xbf,
    u16* __restrict__ wb, float* __restrict__ bkan) {
  __shared__ float sbT[2][128][16];   // 16 KB: transposed basis tile, dbuf
  __shared__ float red[8][16][64];    // 32 KB: cross-wave reduce
  __shared__ float r2[512];
  const int bx = blockIdx.x;
  const int tid = threadIdx.x;
  if (bx < 32) {
    const int w = bx >> 4, dblk = bx & 15;
    const int eg = tid >> 6, dl = tid & 63;
    const int d = dblk * 64 + dl;
    const float* __restrict__ Wp = (w ? Wk : Wq) + d;
    const int sf = tid >> 5, se0 = (tid & 31) * 4;
    {
      float4 bv4 = *(const float4*)(basis + sf * DIM + se0);
      sbT[0][se0 + 0][sf] = bv4.x; sbT[0][se0 + 1][sf] = bv4.y;
      sbT[0][se0 + 2][sf] = bv4.z; sbT[0][se0 + 3][sf] = bv4.w;
    }
    float acc[16];
#pragma unroll
    for (int f = 0; f < 16; ++f) acc[f] = 0.f;
    __syncthreads();
    for (int t = 0; t < 8; ++t) {
      float wv[16];
      const int eb = t * 128 + eg * 16;
#pragma unroll
      for (int u = 0; u < 16; ++u) wv[u] = Wp[(size_t)(eb + u) * DIM];
      float4 nb4;
      if (t < 7)
        nb4 = *(const float4*)(basis + sf * DIM + (t + 1) * 128 + se0);
      const int bufc = t & 1;
#pragma unroll
      for (int u = 0; u < 16; ++u) {
        const float* br = &sbT[bufc][eg * 16 + u][0];
        float4 b0 = *(const float4*)(br + 0);
        float4 b1 = *(const float4*)(br + 4);
        float4 b2 = *(const float4*)(br + 8);
        float4 b3 = *(const float4*)(br + 12);
        acc[0] = fmaf(b0.x, wv[u], acc[0]);
        acc[1] = fmaf(b0.y, wv[u], acc[1]);
        acc[2] = fmaf(b0.z, wv[u], acc[2]);
        acc[3] = fmaf(b0.w, wv[u], acc[3]);
        acc[4] = fmaf(b1.x, wv[u], acc[4]);
        acc[5] = fmaf(b1.y, wv[u], acc[5]);
        acc[6] = fmaf(b1.z, wv[u], acc[6]);
        acc[7] = fmaf(b1.w, wv[u], acc[7]);
        acc[8] = fmaf(b2.x, wv[u], acc[8]);
        acc[9] = fmaf(b2.y, wv[u], acc[9]);
        acc[10] = fmaf(b2.z, wv[u], acc[10]);
        acc[11] = fmaf(b2.w, wv[u], acc[11]);
        acc[12] = fmaf(b3.x, wv[u], acc[12]);
        acc[13] = fmaf(b3.y, wv[u], acc[13]);
        acc[14] = fmaf(b3.z, wv[u], acc[14]);
        acc[15] = fmaf(b3.w, wv[u], acc[15]);
      }
      __syncthreads();
      if (t < 7) {
        const int nb_ = (t + 1) & 1;
        sbT[nb_][se0 + 0][sf] = nb4.x; sbT[nb_][se0 + 1][sf] = nb4.y;
        sbT[nb_][se0 + 2][sf] = nb4.z; sbT[nb_][se0 + 3][sf] = nb4.w;
        __syncthreads();
      }
    }
#pragma unroll
    for (int f = 0; f < 16; ++f) red[eg][f][dl] = acc[f];
    __syncthreads();
#pragma unroll
    for (int r = 0; r < 2; ++r) {
      const int o = r * 512 + tid;        // 0..1023
      const int f = o >> 6, dd = o & 63;
      float s = 0.f;
#pragma unroll
      for (int g = 0; g < 8; ++g) s += red[g][f][dd];
      wb[(size_t)(1024 + w * 16 + f) * DIM + dblk * 64 + dd] = f2bf(s);
    }
  } else if (bx == 32) {
    const int w2 = tid >> 8, f = (tid >> 4) & 15, eg = tid & 15;
    const float* __restrict__ bb = w2 ? bk : bq;
    float a = 0.f;
    for (int e = eg * 64; e < eg * 64 + 64; ++e)
      a = fmaf(basis[f * DIM + e], bb[e], a);
    r2[tid] = a;
    __syncthreads();
    if ((tid & 15) == 0) {
      float s = 0.f;
#pragma unroll
      for (int i = 0; i < 16; ++i) s += r2[tid + i];
      bkan[tid >> 4] = s;
    }
  } else if (bx < 2081) {
    const int i = ((bx - 33) * 512 + tid) * 8;
    float4 a = *(const float4*)(x + i);
    float4 b = *(const float4*)(x + i + 4);
    short8 o;
    o[0] = f2bf(a.x); o[1] = f2bf(a.y); o[2] = f2bf(a.z); o[3] = f2bf(a.w);
    o[4] = f2bf(b.x); o[5] = f2bf(b.y); o[6] = f2bf(b.z); o[7] = f2bf(b.w);
    *(short8*)(xbf + i) = o;
  } else {
    const int i = ((bx - 2081) * 512 + tid) * 8;
    float4 a = *(const float4*)(Wv + i);
    float4 b = *(const float4*)(Wv + i + 4);
    short8 o;
    o[0] = f2bf(a.x); o[1] = f2bf(a.y); o[2] = f2bf(a.z); o[3] = f2bf(a.w);
    o[4] = f2bf(b.x); o[5] = f2bf(b.y); o[6] = f2bf(b.z); o[7] = f2bf(b.w);
    *(short8*)(wb + i) = o;
  }
}

// ---------------------------------------------------------------------------
// bf16 MFMA GEMM, XCD-aware swizzle: xcd = bx&7 owns nb in {xcd, xcd+8, ...}
// -> per-XCD L2 working set = 8 A-tiles (2 MB) + B (2.4 MB). Epilogue:
// V transposed + m-bit-swap (2<->3); kanq (x 1/32) / kank. grid 576 linear.
// ---------------------------------------------------------------------------
__device__ __forceinline__ void gll16(const void* g, void* s) {
  __builtin_amdgcn_global_load_lds(
      (const __attribute__((address_space(1))) void*)g,
      (__attribute__((address_space(3))) void*)s, 16, 0, 0);
}

__global__ __launch_bounds__(256) void k_gemm(
    const u16* __restrict__ A, const u16* __restrict__ B,
    const float* __restrict__ bv, const float* __restrict__ bkan,
    u16* __restrict__ vt, u16* __restrict__ kanq, u16* __restrict__ kank) {
  __shared__ u16 As[128 * 64];
  __shared__ u16 Bs[128 * 64];
  const int bx = blockIdx.x;
  const int xcd = bx & 7, s = bx >> 3;
  const int nb = xcd + 8 * (s / 9);    // A row-tile: stays on this XCD
  const int jb = s % 9;
  const int tid = threadIdx.x;
  const int w = tid >> 6, l = tid & 63;
  const int wr = w >> 1, wc = w & 1;
  const int lq = l & 15, quad = l >> 4;
  const int srow = l >> 3, scol = (l & 7) * 8;
  const u16* Ab = A + (size_t)(nb * 128 + w * 8 + srow) * DIM + scol;
  const u16* Bb = B + (size_t)(jb * 128 + w * 8 + srow) * DIM + scol;
  floatx4 acc[4][4];
  const floatx4 z4 = {0.f, 0.f, 0.f, 0.f};
#pragma unroll
  for (int i = 0; i < 4; ++i)
#pragma unroll
    for (int j = 0; j < 4; ++j) acc[i][j] = z4;

  for (int k0 = 0; k0 < DIM; k0 += 64) {
    __syncthreads();
#pragma unroll
    for (int i = 0; i < 4; ++i) {
      gll16(Ab + (size_t)i * 32 * DIM + k0, &As[(i * 32 + w * 8) * 64]);
      gll16(Bb + (size_t)i * 32 * DIM + k0, &Bs[(i * 32 + w * 8) * 64]);
    }
    __syncthreads();
#pragma unroll
    for (int kk = 0; kk < 64; kk += 32) {
      short8 af[4], bf[4];
#pragma unroll
      for (int t = 0; t < 4; ++t)
        af[t] = *(const short8*)&As[(wr * 64 + t * 16 + lq) * 64 + kk + quad * 8];
#pragma unroll
      for (int t = 0; t < 4; ++t)
        bf[t] = *(const short8*)&Bs[(wc * 64 + t * 16 + lq) * 64 + kk + quad * 8];
#pragma unroll
      for (int rt = 0; rt < 4; ++rt)
#pragma unroll
        for (int ct = 0; ct < 4; ++ct)
          acc[rt][ct] = __builtin_amdgcn_mfma_f32_16x16x32_bf16(
              af[rt], bf[ct], acc[rt][ct], 0, 0, 0);
    }
  }

  const int bt = nb >> 4;  // batch (128-row blocks never straddle)
  const size_t vtB = (size_t)bt * DIM * SEQ;
#pragma unroll
  for (int ct = 0; ct < 4; ++ct) {
    const int jbase = jb * 128 + wc * 64 + ct * 16;
    if (jbase >= 1056) continue;
    const int j = jbase + lq;
    const float bias = (jbase < 1024) ? bv[j] : bkan[j - 1024];
#pragma unroll
    for (int rt = 0; rt < 4; ++rt) {
      const int t0 = nb * 128 + wr * 64 + rt * 16 + quad * 4;
      if (jbase < 1024) {
        short4v pk;
        pk[0] = (short)f2bf(acc[rt][ct][0] + bias);
        pk[1] = (short)f2bf(acc[rt][ct][1] + bias);
        pk[2] = (short)f2bf(acc[rt][ct][2] + bias);
        pk[3] = (short)f2bf(acc[rt][ct][3] + bias);
        const int mloc = t0 & (SEQ - 1);
        const int mperm =
            (mloc & ~12) | ((mloc & 4) << 1) | ((mloc & 8) >> 1);
        *(short4v*)(vt + vtB + (size_t)j * SEQ + mperm) = pk;
      } else if (jbase < 1040) {
        const int f = j - 1024;
#pragma unroll
        for (int r = 0; r < 4; ++r)
          kanq[(size_t)(t0 + r) * 16 + f] =
              f2bf((acc[rt][ct][r] + bias) * 0.03125f);
      } else {
        const int f = j - 1040;
#pragma unroll
        for (int r = 0; r < 4; ++r)
          kank[(size_t)(t0 + r) * 16 + f] = f2bf(acc[rt][ct][r] + bias);
      }
    }
  }
}

// ---------------------------------------------------------------------------
// k_pv v5 (unchanged): vt pre-permuted; staging 4 b128 reads + 4 b128 LDS
// writes; A-frags single b128 at VST=88. Cubic exp, v_perm pack, L via
// ones-MFMA. One barrier per 64 m. Block = 128q x 128d, grid 512.
// ---------------------------------------------------------------------------
#define VST 88  // u16 row stride: 176 B, 16B-aligned

__global__ __launch_bounds__(256, 2) void k_pv(const u16* __restrict__ vt,
                                               const u16* __restrict__ kanq,
                                               const u16* __restrict__ kank,
                                               float* __restrict__ out) {
  __shared__ u16 Vs[2][128 * VST];
  const int bx = blockIdx.x;
  const int qb = bx >> 5;
  const int g = bx & 31;
  const int b = g >> 3, ds = g & 7;
  const int q0 = qb * 128, d0 = ds * 128;
  const int tid = threadIdx.x, w = tid >> 6, l = tid & 63;
  const int lq = l & 31, h = l >> 5;
  const u16* kq = kanq + (size_t)b * SEQ * 16;
  const u16* kk = kank + (size_t)b * SEQ * 16;
  const u16* vtb = vt + ((size_t)b * DIM + d0) * SEQ;

  const short8 bqf =
      *(const short8*)(kq + (size_t)(q0 + w * 32 + lq) * 16 + h * 8);

  const int srow = tid >> 1, sc_ = tid & 1;
  const u16* sgp = vtb + (size_t)srow * SEQ + sc_ * 32;
  u16* const slA = &Vs[0][srow * VST + sc_ * 32];
  u16* const slB = &Vs[1][srow * VST + sc_ * 32];

  short8 ones;
#pragma unroll
  for (int i = 0; i < 8; ++i) ones[i] = (short)0x3F80;

  const floatx16 z16 = {0.f,0.f,0.f,0.f,0.f,0.f,0.f,0.f,
                        0.f,0.f,0.f,0.f,0.f,0.f,0.f,0.f};
  floatx16 accO[4], accL = z16;
#pragma unroll
  for (int dt = 0; dt < 4; ++dt) accO[dt] = z16;

  {
    short8 va = *(const short8*)(sgp);
    short8 vb_ = *(const short8*)(sgp + 8);
    short8 vc = *(const short8*)(sgp + 16);
    short8 vd = *(const short8*)(sgp + 24);
    *(short8*)(slA + 0) = va;
    *(short8*)(slA + 8) = vb_;
    *(short8*)(slA + 16) = vc;
    *(short8*)(slA + 24) = vd;
  }
  short8 kkA = *(const short8*)(kk + (size_t)(0 + lq) * 16 + h * 8);
  short8 kkB = *(const short8*)(kk + (size_t)(32 + lq) * 16 + h * 8);
  __syncthreads();

  for (int it = 0; it < SEQ / 64; ++it) {
    const int mn = (it + 1 < SEQ / 64) ? (it + 1) * 64 : 0;
    short8 nva = *(const short8*)(sgp + mn);
    short8 nvb = *(const short8*)(sgp + mn + 8);
    short8 nvc = *(const short8*)(sgp + mn + 16);
    short8 nvd = *(const short8*)(sgp + mn + 24);
    const short8 kkcA = kkA, kkcB = kkB;
    kkA = *(const short8*)(kk + (size_t)(mn + lq) * 16 + h * 8);
    kkB = *(const short8*)(kk + (size_t)(mn + 32 + lq) * 16 + h * 8);

    floatx16 scA =
        __builtin_amdgcn_mfma_f32_32x32x16_bf16(kkcA, bqf, z16, 0, 0, 0);
    floatx16 scB =
        __builtin_amdgcn_mfma_f32_32x32x16_bf16(kkcB, bqf, z16, 0, 0, 0);

    short8 p1A, p2A, p1B, p2B;
    {
      float eA[16], eB[16];
#pragma unroll
      for (int i = 0; i < 16; ++i) {
        float xa = scA[i], xb = scB[i];
        eA[i] = fmaf(xa, fmaf(xa, fmaf(xa, 0.16666667f, 0.5f), 1.0f), 1.0f);
        eB[i] = fmaf(xb, fmaf(xb, fmaf(xb, 0.16666667f, 0.5f), 1.0f), 1.0f);
      }
      union { unsigned i[4]; short8 v; } u1a, u2a, u1b, u2b;
#pragma unroll
      for (int j = 0; j < 4; ++j) {
        u1a.i[j] = __builtin_amdgcn_perm(fbits(eA[2 * j + 1]), fbits(eA[2 * j]),
                                         0x07060302u);
        u2a.i[j] = __builtin_amdgcn_perm(fbits(eA[8 + 2 * j + 1]),
                                         fbits(eA[8 + 2 * j]), 0x07060302u);
        u1b.i[j] = __builtin_amdgcn_perm(fbits(eB[2 * j + 1]), fbits(eB[2 * j]),
                                         0x07060302u);
        u2b.i[j] = __builtin_amdgcn_perm(fbits(eB[8 + 2 * j + 1]),
                                         fbits(eB[8 + 2 * j]), 0x07060302u);
      }
      p1A = u1a.v; p2A = u2a.v; p1B = u1b.v; p2B = u2b.v;
    }

    accL = __builtin_amdgcn_mfma_f32_32x32x16_bf16(ones, p1A, accL, 0, 0, 0);
    accL = __builtin_amdgcn_mfma_f32_32x32x16_bf16(ones, p2A, accL, 0, 0, 0);
    accL = __builtin_amdgcn_mfma_f32_32x32x16_bf16(ones, p1B, accL, 0, 0, 0);
    accL = __builtin_amdgcn_mfma_f32_32x32x16_bf16(ones, p2B, accL, 0, 0, 0);

    const u16* vb = &Vs[it & 1][0];
#pragma unroll
    for (int dt = 0; dt < 4; ++dt) {
      const int r = (dt * 32 + lq) * VST + h * 8;
      short8 a1 = *(const short8*)(vb + r);
      short8 a2 = *(const short8*)(vb + r + 16);
      short8 a3 = *(const short8*)(vb + r + 32);
      short8 a4 = *(const short8*)(vb + r + 48);
      accO[dt] = __builtin_amdgcn_mfma_f32_32x32x16_bf16(a1, p1A, accO[dt], 0, 0, 0);
      accO[dt] = __builtin_amdgcn_mfma_f32_32x32x16_bf16(a2, p2A, accO[dt], 0, 0, 0);
      accO[dt] = __builtin_amdgcn_mfma_f32_32x32x16_bf16(a3, p1B, accO[dt], 0, 0, 0);
      accO[dt] = __builtin_amdgcn_mfma_f32_32x32x16_bf16(a4, p2B, accO[dt], 0, 0, 0);
    }

    u16* sl = (it & 1) ? slA : slB;
    *(short8*)(sl + 0) = nva;
    *(short8*)(sl + 8) = nvb;
    *(short8*)(sl + 16) = nvc;
    *(short8*)(sl + 24) = nvd;
    __syncthreads();
  }

  const float rinv = 1.f / accL[0];
  float* ob = out + ((size_t)b * SEQ + q0 + w * 32 + lq) * DIM + d0;
#pragma unroll
  for (int dt = 0; dt < 4; ++dt) {
#pragma unroll
    for (int gi = 0; gi < 4; ++gi) {
      float4 o;
      o.x = accO[dt][gi * 4 + 0] * rinv;
      o.y = accO[dt][gi * 4 + 1] * rinv;
      o.z = accO[dt][gi * 4 + 2] * rinv;
      o.w = accO[dt][gi * 4 + 3] * rinv;
      *(float4*)(ob + dt * 32 + gi * 8 + h * 4) = o;
    }
  }
}

// ---------------------------------------------------------------------------
extern "C" void kernel_launch(void* const* d_in, const int* in_sizes, int n_in,
                              void* d_out, int out_size, void* d_ws,
                              size_t ws_size, hipStream_t stream) {
  const float* x = (const float*)d_in[0];
  const float* basis = (const float*)d_in[1];
  const float* Wq = (const float*)d_in[2];
  const float* bq = (const float*)d_in[3];
  const float* Wk = (const float*)d_in[4];
  const float* bk = (const float*)d_in[5];
  const float* Wv = (const float*)d_in[6];
  const float* bv = (const float*)d_in[7];
  float* out = (float*)d_out;
  char* w8 = (char*)d_ws;
  u16* xbf = (u16*)(w8 + OFF_XBF);
  u16* vt = (u16*)(w8 + OFF_VT);
  u16* wb = (u16*)(w8 + OFF_WB);
  u16* kanq = (u16*)(w8 + OFF_KANQ);
  u16* kank = (u16*)(w8 + OFF_KANK);
  float* bkan = (float*)(w8 + OFF_BKAN);

  k_misc<<<2337, 512, 0, stream>>>(x, basis, Wq, bq, Wk, bk, Wv, xbf, wb, bkan);
  k_gemm<<<576, 256, 0, stream>>>(xbf, wb, bv, bkan, vt, kanq, kank);
  k_pv<<<512, 256, 0, stream>>>(vt, kanq, kank, out);
}

// Round 7
// 191.067 us; speedup vs baseline: 1.0853x; 1.0853x over previous
//
#include <hip/hip_runtime.h>
#include <math.h>

typedef unsigned short u16;
typedef __attribute__((ext_vector_type(8))) short short8;    // 8 bf16 = 4 VGPR
typedef __attribute__((ext_vector_type(4))) short short4v;   // 4 bf16 = 2 VGPR
typedef __attribute__((ext_vector_type(4))) float floatx4;   // 16x16 MFMA C/D
typedef __attribute__((ext_vector_type(16))) float floatx16; // 32x32 MFMA C/D

#define DIM 1024
#define SEQ 2048
#define BATCH 4
#define NTOK 8192

// workspace layout (bytes)
#define OFF_XBF   0u
#define OFF_VT    16777216u
#define OFF_WB    33554432u   // 1152 x 1024 bf16 (rows 1056+ never written: poison, discarded)
#define OFF_KANQ  35913728u   // 8192 x 16 bf16
#define OFF_KANK  36438016u
#define OFF_BKAN  36962304u   // 32 floats

__device__ __forceinline__ u16 f2bf(float x) {
  union { float f; unsigned u; } v; v.f = x;
  unsigned r = v.u + 0x7fffu + ((v.u >> 16) & 1u);   // RNE
  return (u16)(r >> 16);
}
__device__ __forceinline__ unsigned fbits(float x) {
  union { float f; unsigned u; } v; v.f = x; return v.u;
}

// ---------------------------------------------------------------------------
// k_misc: one launch for all prep (512 threads/block). (unchanged)
// ---------------------------------------------------------------------------
__global__ __launch_bounds__(512) void k_misc(
    const float* __restrict__ x, const float* __restrict__ basis,
    const float* __restrict__ Wq, const float* __restrict__ bq,
    const float* __restrict__ Wk, const float* __restrict__ bk,
    const float* __restrict__ Wv, u16* __restrict__ xbf,
    u16* __restrict__ wb, float* __restrict__ bkan) {
  __shared__ float sbT[2][128][16];   // 16 KB: transposed basis tile, dbuf
  __shared__ float red[8][16][64];    // 32 KB: cross-wave reduce
  __shared__ float r2[512];
  const int bx = blockIdx.x;
  const int tid = threadIdx.x;
  if (bx < 32) {
    const int w = bx >> 4, dblk = bx & 15;
    const int eg = tid >> 6, dl = tid & 63;
    const int d = dblk * 64 + dl;
    const float* __restrict__ Wp = (w ? Wk : Wq) + d;
    const int sf = tid >> 5, se0 = (tid & 31) * 4;
    {
      float4 bv4 = *(const float4*)(basis + sf * DIM + se0);
      sbT[0][se0 + 0][sf] = bv4.x; sbT[0][se0 + 1][sf] = bv4.y;
      sbT[0][se0 + 2][sf] = bv4.z; sbT[0][se0 + 3][sf] = bv4.w;
    }
    float acc[16];
#pragma unroll
    for (int f = 0; f < 16; ++f) acc[f] = 0.f;
    __syncthreads();
    for (int t = 0; t < 8; ++t) {
      float wv[16];
      const int eb = t * 128 + eg * 16;
#pragma unroll
      for (int u = 0; u < 16; ++u) wv[u] = Wp[(size_t)(eb + u) * DIM];
      float4 nb4;
      if (t < 7)
        nb4 = *(const float4*)(basis + sf * DIM + (t + 1) * 128 + se0);
      const int bufc = t & 1;
#pragma unroll
      for (int u = 0; u < 16; ++u) {
        const float* br = &sbT[bufc][eg * 16 + u][0];
        float4 b0 = *(const float4*)(br + 0);
        float4 b1 = *(const float4*)(br + 4);
        float4 b2 = *(const float4*)(br + 8);
        float4 b3 = *(const float4*)(br + 12);
        acc[0] = fmaf(b0.x, wv[u], acc[0]);
        acc[1] = fmaf(b0.y, wv[u], acc[1]);
        acc[2] = fmaf(b0.z, wv[u], acc[2]);
        acc[3] = fmaf(b0.w, wv[u], acc[3]);
        acc[4] = fmaf(b1.x, wv[u], acc[4]);
        acc[5] = fmaf(b1.y, wv[u], acc[5]);
        acc[6] = fmaf(b1.z, wv[u], acc[6]);
        acc[7] = fmaf(b1.w, wv[u], acc[7]);
        acc[8] = fmaf(b2.x, wv[u], acc[8]);
        acc[9] = fmaf(b2.y, wv[u], acc[9]);
        acc[10] = fmaf(b2.z, wv[u], acc[10]);
        acc[11] = fmaf(b2.w, wv[u], acc[11]);
        acc[12] = fmaf(b3.x, wv[u], acc[12]);
        acc[13] = fmaf(b3.y, wv[u], acc[13]);
        acc[14] = fmaf(b3.z, wv[u], acc[14]);
        acc[15] = fmaf(b3.w, wv[u], acc[15]);
      }
      __syncthreads();
      if (t < 7) {
        const int nb_ = (t + 1) & 1;
        sbT[nb_][se0 + 0][sf] = nb4.x; sbT[nb_][se0 + 1][sf] = nb4.y;
        sbT[nb_][se0 + 2][sf] = nb4.z; sbT[nb_][se0 + 3][sf] = nb4.w;
        __syncthreads();
      }
    }
#pragma unroll
    for (int f = 0; f < 16; ++f) red[eg][f][dl] = acc[f];
    __syncthreads();
#pragma unroll
    for (int r = 0; r < 2; ++r) {
      const int o = r * 512 + tid;        // 0..1023
      const int f = o >> 6, dd = o & 63;
      float s = 0.f;
#pragma unroll
      for (int g = 0; g < 8; ++g) s += red[g][f][dd];
      wb[(size_t)(1024 + w * 16 + f) * DIM + dblk * 64 + dd] = f2bf(s);
    }
  } else if (bx == 32) {
    const int w2 = tid >> 8, f = (tid >> 4) & 15, eg = tid & 15;
    const float* __restrict__ bb = w2 ? bk : bq;
    float a = 0.f;
    for (int e = eg * 64; e < eg * 64 + 64; ++e)
      a = fmaf(basis[f * DIM + e], bb[e], a);
    r2[tid] = a;
    __syncthreads();
    if ((tid & 15) == 0) {
      float s = 0.f;
#pragma unroll
      for (int i = 0; i < 16; ++i) s += r2[tid + i];
      bkan[tid >> 4] = s;
    }
  } else if (bx < 2081) {
    const int i = ((bx - 33) * 512 + tid) * 8;
    float4 a = *(const float4*)(x + i);
    float4 b = *(const float4*)(x + i + 4);
    short8 o;
    o[0] = f2bf(a.x); o[1] = f2bf(a.y); o[2] = f2bf(a.z); o[3] = f2bf(a.w);
    o[4] = f2bf(b.x); o[5] = f2bf(b.y); o[6] = f2bf(b.z); o[7] = f2bf(b.w);
    *(short8*)(xbf + i) = o;
  } else {
    const int i = ((bx - 2081) * 512 + tid) * 8;
    float4 a = *(const float4*)(Wv + i);
    float4 b = *(const float4*)(Wv + i + 4);
    short8 o;
    o[0] = f2bf(a.x); o[1] = f2bf(a.y); o[2] = f2bf(a.z); o[3] = f2bf(a.w);
    o[4] = f2bf(b.x); o[5] = f2bf(b.y); o[6] = f2bf(b.z); o[7] = f2bf(b.w);
    *(short8*)(wb + i) = o;
  }
}

// ---------------------------------------------------------------------------
// bf16 MFMA GEMM v7: 64x128 tile (grid 1152 = 4.5 blocks/CU), XCD swizzle,
// XOR-swizzled LDS 16B segments (bank-conflict-free reads: the per-lane
// GLOBAL address carries the swizzle, LDS dest stays wave-uniform+lane*16).
// Epilogue: V transposed + m-bit-swap(2<->3); kanq (x 1/32) / kank.
// ---------------------------------------------------------------------------
__device__ __forceinline__ void gll16(const void* g, void* s) {
  __builtin_amdgcn_global_load_lds(
      (const __attribute__((address_space(1))) void*)g,
      (__attribute__((address_space(3))) void*)s, 16, 0, 0);
}

__global__ __launch_bounds__(256) void k_gemm(
    const u16* __restrict__ A, const u16* __restrict__ B,
    const float* __restrict__ bv, const float* __restrict__ bkan,
    u16* __restrict__ vt, u16* __restrict__ kanq, u16* __restrict__ kank) {
  __shared__ u16 As[64 * 64];    //  8 KB
  __shared__ u16 Bs[128 * 64];   // 16 KB
  const int bx = blockIdx.x;
  const int xcd = bx & 7, s = bx >> 3;
  const int nb = xcd + 8 * (s / 9);    // 0..127 (64-row A tile, XCD-resident)
  const int jb = s % 9;
  const int tid = threadIdx.x;
  const int w = tid >> 6, l = tid & 63;
  const int wr = w >> 1, wc = w & 1;   // wave tile: 32 rows x 64 cols
  const int lq = l & 15, quad = l >> 4;
  const int srow = l >> 3;                          // 0..7 within 8-row chunk
  const int scol = ((l & 7) ^ (srow & 7)) * 8;      // XOR-swizzled 16B segment
  const u16* Ab = A + (size_t)(nb * 64 + w * 8 + srow) * DIM + scol;
  const u16* Bb = B + (size_t)(jb * 128 + w * 8 + srow) * DIM + scol;
  floatx4 acc[2][4];
  const floatx4 z4 = {0.f, 0.f, 0.f, 0.f};
#pragma unroll
  for (int i = 0; i < 2; ++i)
#pragma unroll
    for (int j = 0; j < 4; ++j) acc[i][j] = z4;

  for (int k0 = 0; k0 < DIM; k0 += 64) {
    __syncthreads();
#pragma unroll
    for (int i = 0; i < 2; ++i)
      gll16(Ab + (size_t)i * 32 * DIM + k0, &As[(i * 32 + w * 8) * 64]);
#pragma unroll
    for (int i = 0; i < 4; ++i)
      gll16(Bb + (size_t)i * 32 * DIM + k0, &Bs[(i * 32 + w * 8) * 64]);
    __syncthreads();
#pragma unroll
    for (int kk = 0; kk < 64; kk += 32) {
      const int sbase = (kk >> 3) + quad;           // 16B segment wanted
      const int slot = (sbase ^ (lq & 7)) * 8;      // swizzled LDS slot
      short8 af[2], bf[4];
#pragma unroll
      for (int t = 0; t < 2; ++t)
        af[t] = *(const short8*)&As[(wr * 32 + t * 16 + lq) * 64 + slot];
#pragma unroll
      for (int t = 0; t < 4; ++t)
        bf[t] = *(const short8*)&Bs[(wc * 64 + t * 16 + lq) * 64 + slot];
#pragma unroll
      for (int rt = 0; rt < 2; ++rt)
#pragma unroll
        for (int ct = 0; ct < 4; ++ct)
          acc[rt][ct] = __builtin_amdgcn_mfma_f32_16x16x32_bf16(
              af[rt], bf[ct], acc[rt][ct], 0, 0, 0);
    }
  }

  const int bt = nb >> 5;  // batch (64-row blocks never straddle: 2048/64=32)
  const size_t vtB = (size_t)bt * DIM * SEQ;
#pragma unroll
  for (int ct = 0; ct < 4; ++ct) {
    const int jbase = jb * 128 + wc * 64 + ct * 16;
    if (jbase >= 1056) continue;
    const int j = jbase + lq;
    const float bias = (jbase < 1024) ? bv[j] : bkan[j - 1024];
#pragma unroll
    for (int rt = 0; rt < 2; ++rt) {
      const int t0 = nb * 64 + wr * 32 + rt * 16 + quad * 4;
      if (jbase < 1024) {
        short4v pk;
        pk[0] = (short)f2bf(acc[rt][ct][0] + bias);
        pk[1] = (short)f2bf(acc[rt][ct][1] + bias);
        pk[2] = (short)f2bf(acc[rt][ct][2] + bias);
        pk[3] = (short)f2bf(acc[rt][ct][3] + bias);
        const int mloc = t0 & (SEQ - 1);
        const int mperm =
            (mloc & ~12) | ((mloc & 4) << 1) | ((mloc & 8) >> 1);
        *(short4v*)(vt + vtB + (size_t)j * SEQ + mperm) = pk;
      } else if (jbase < 1040) {
        const int f = j - 1024;
#pragma unroll
        for (int r = 0; r < 4; ++r)
          kanq[(size_t)(t0 + r) * 16 + f] =
              f2bf((acc[rt][ct][r] + bias) * 0.03125f);
      } else {
        const int f = j - 1040;
#pragma unroll
        for (int r = 0; r < 4; ++r)
          kank[(size_t)(t0 + r) * 16 + f] = f2bf(acc[rt][ct][r] + bias);
      }
    }
  }
}

// ---------------------------------------------------------------------------
// k_pv v5 (unchanged): vt pre-permuted; staging 4 b128 reads + 4 b128 LDS
// writes; A-frags single b128 at VST=88. Cubic exp, v_perm pack, L via
// ones-MFMA. One barrier per 64 m. Block = 128q x 128d, grid 512.
// ---------------------------------------------------------------------------
#define VST 88  // u16 row stride: 176 B, 16B-aligned

__global__ __launch_bounds__(256, 2) void k_pv(const u16* __restrict__ vt,
                                               const u16* __restrict__ kanq,
                                               const u16* __restrict__ kank,
                                               float* __restrict__ out) {
  __shared__ u16 Vs[2][128 * VST];
  const int bx = blockIdx.x;
  const int qb = bx >> 5;
  const int g = bx & 31;
  const int b = g >> 3, ds = g & 7;
  const int q0 = qb * 128, d0 = ds * 128;
  const int tid = threadIdx.x, w = tid >> 6, l = tid & 63;
  const int lq = l & 31, h = l >> 5;
  const u16* kq = kanq + (size_t)b * SEQ * 16;
  const u16* kk = kank + (size_t)b * SEQ * 16;
  const u16* vtb = vt + ((size_t)b * DIM + d0) * SEQ;

  const short8 bqf =
      *(const short8*)(kq + (size_t)(q0 + w * 32 + lq) * 16 + h * 8);

  const int srow = tid >> 1, sc_ = tid & 1;
  const u16* sgp = vtb + (size_t)srow * SEQ + sc_ * 32;
  u16* const slA = &Vs[0][srow * VST + sc_ * 32];
  u16* const slB = &Vs[1][srow * VST + sc_ * 32];

  short8 ones;
#pragma unroll
  for (int i = 0; i < 8; ++i) ones[i] = (short)0x3F80;

  const floatx16 z16 = {0.f,0.f,0.f,0.f,0.f,0.f,0.f,0.f,
                        0.f,0.f,0.f,0.f,0.f,0.f,0.f,0.f};
  floatx16 accO[4], accL = z16;
#pragma unroll
  for (int dt = 0; dt < 4; ++dt) accO[dt] = z16;

  {
    short8 va = *(const short8*)(sgp);
    short8 vb_ = *(const short8*)(sgp + 8);
    short8 vc = *(const short8*)(sgp + 16);
    short8 vd = *(const short8*)(sgp + 24);
    *(short8*)(slA + 0) = va;
    *(short8*)(slA + 8) = vb_;
    *(short8*)(slA + 16) = vc;
    *(short8*)(slA + 24) = vd;
  }
  short8 kkA = *(const short8*)(kk + (size_t)(0 + lq) * 16 + h * 8);
  short8 kkB = *(const short8*)(kk + (size_t)(32 + lq) * 16 + h * 8);
  __syncthreads();

  for (int it = 0; it < SEQ / 64; ++it) {
    const int mn = (it + 1 < SEQ / 64) ? (it + 1) * 64 : 0;
    short8 nva = *(const short8*)(sgp + mn);
    short8 nvb = *(const short8*)(sgp + mn + 8);
    short8 nvc = *(const short8*)(sgp + mn + 16);
    short8 nvd = *(const short8*)(sgp + mn + 24);
    const short8 kkcA = kkA, kkcB = kkB;
    kkA = *(const short8*)(kk + (size_t)(mn + lq) * 16 + h * 8);
    kkB = *(const short8*)(kk + (size_t)(mn + 32 + lq) * 16 + h * 8);

    floatx16 scA =
        __builtin_amdgcn_mfma_f32_32x32x16_bf16(kkcA, bqf, z16, 0, 0, 0);
    floatx16 scB =
        __builtin_amdgcn_mfma_f32_32x32x16_bf16(kkcB, bqf, z16, 0, 0, 0);

    short8 p1A, p2A, p1B, p2B;
    {
      float eA[16], eB[16];
#pragma unroll
      for (int i = 0; i < 16; ++i) {
        float xa = scA[i], xb = scB[i];
        eA[i] = fmaf(xa, fmaf(xa, fmaf(xa, 0.16666667f, 0.5f), 1.0f), 1.0f);
        eB[i] = fmaf(xb, fmaf(xb, fmaf(xb, 0.16666667f, 0.5f), 1.0f), 1.0f);
      }
      union { unsigned i[4]; short8 v; } u1a, u2a, u1b, u2b;
#pragma unroll
      for (int j = 0; j < 4; ++j) {
        u1a.i[j] = __builtin_amdgcn_perm(fbits(eA[2 * j + 1]), fbits(eA[2 * j]),
                                         0x07060302u);
        u2a.i[j] = __builtin_amdgcn_perm(fbits(eA[8 + 2 * j + 1]),
                                         fbits(eA[8 + 2 * j]), 0x07060302u);
        u1b.i[j] = __builtin_amdgcn_perm(fbits(eB[2 * j + 1]), fbits(eB[2 * j]),
                                         0x07060302u);
        u2b.i[j] = __builtin_amdgcn_perm(fbits(eB[8 + 2 * j + 1]),
                                         fbits(eB[8 + 2 * j]), 0x07060302u);
      }
      p1A = u1a.v; p2A = u2a.v; p1B = u1b.v; p2B = u2b.v;
    }

    accL = __builtin_amdgcn_mfma_f32_32x32x16_bf16(ones, p1A, accL, 0, 0, 0);
    accL = __builtin_amdgcn_mfma_f32_32x32x16_bf16(ones, p2A, accL, 0, 0, 0);
    accL = __builtin_amdgcn_mfma_f32_32x32x16_bf16(ones, p1B, accL, 0, 0, 0);
    accL = __builtin_amdgcn_mfma_f32_32x32x16_bf16(ones, p2B, accL, 0, 0, 0);

    const u16* vb = &Vs[it & 1][0];
#pragma unroll
    for (int dt = 0; dt < 4; ++dt) {
      const int r = (dt * 32 + lq) * VST + h * 8;
      short8 a1 = *(const short8*)(vb + r);
      short8 a2 = *(const short8*)(vb + r + 16);
      short8 a3 = *(const short8*)(vb + r + 32);
      short8 a4 = *(const short8*)(vb + r + 48);
      accO[dt] = __builtin_amdgcn_mfma_f32_32x32x16_bf16(a1, p1A, accO[dt], 0, 0, 0);
      accO[dt] = __builtin_amdgcn_mfma_f32_32x32x16_bf16(a2, p2A, accO[dt], 0, 0, 0);
      accO[dt] = __builtin_amdgcn_mfma_f32_32x32x16_bf16(a3, p1B, accO[dt], 0, 0, 0);
      accO[dt] = __builtin_amdgcn_mfma_f32_32x32x16_bf16(a4, p2B, accO[dt], 0, 0, 0);
    }

    u16* sl = (it & 1) ? slA : slB;
    *(short8*)(sl + 0) = nva;
    *(short8*)(sl + 8) = nvb;
    *(short8*)(sl + 16) = nvc;
    *(short8*)(sl + 24) = nvd;
    __syncthreads();
  }

  const float rinv = 1.f / accL[0];
  float* ob = out + ((size_t)b * SEQ + q0 + w * 32 + lq) * DIM + d0;
#pragma unroll
  for (int dt = 0; dt < 4; ++dt) {
#pragma unroll
    for (int gi = 0; gi < 4; ++gi) {
      float4 o;
      o.x = accO[dt][gi * 4 + 0] * rinv;
      o.y = accO[dt][gi * 4 + 1] * rinv;
      o.z = accO[dt][gi * 4 + 2] * rinv;
      o.w = accO[dt][gi * 4 + 3] * rinv;
      *(float4*)(ob + dt * 32 + gi * 8 + h * 4) = o;
    }
  }
}

// ---------------------------------------------------------------------------
extern "C" void kernel_launch(void* const* d_in, const int* in_sizes, int n_in,
                              void* d_out, int out_size, void* d_ws,
                              size_t ws_size, hipStream_t stream) {
  const float* x = (const float*)d_in[0];
  const float* basis = (const float*)d_in[1];
  const float* Wq = (const float*)d_in[2];
  const float* bq = (const float*)d_in[3];
  const float* Wk = (const float*)d_in[4];
  const float* bk = (const float*)d_in[5];
  const float* Wv = (const float*)d_in[6];
  const float* bv = (const float*)d_in[7];
  float* out = (float*)d_out;
  char* w8 = (char*)d_ws;
  u16* xbf = (u16*)(w8 + OFF_XBF);
  u16* vt = (u16*)(w8 + OFF_VT);
  u16* wb = (u16*)(w8 + OFF_WB);
  u16* kanq = (u16*)(w8 + OFF_KANQ);
  u16* kank = (u16*)(w8 + OFF_KANK);
  float* bkan = (float*)(w8 + OFF_BKAN);

  k_misc<<<2337, 512, 0, stream>>>(x, basis, Wq, bq, Wk, bk, Wv, xbf, wb, bkan);
  k_gemm<<<1152, 256, 0, stream>>>(xbf, wb, bv, bkan, vt, kanq, kank);
  k_pv<<<512, 256, 0, stream>>>(vt, kanq, kank, out);
}